// Round 6
// baseline (680.051 us; speedup 1.0000x reference)
//
#include <hip/hip_runtime.h>
#include <hip/hip_bf16.h>

#define NN 50000
#define NE 1600000
#define FEAT 128
#define NG 128
#define NC 10

constexpr int SCAN_BLOCKS = (NN + 255) / 256; // 196

// ---------------- bf16 helpers (manual, RNE) ----------------
__device__ __forceinline__ float bflo(unsigned u) { return __uint_as_float(u << 16); }
__device__ __forceinline__ float bfhi(unsigned u) { return __uint_as_float(u & 0xffff0000u); }
__device__ __forceinline__ float bfs(unsigned short u) { return __uint_as_float(((unsigned)u) << 16); }
__device__ __forceinline__ unsigned packbf(float a, float b) {
    unsigned ua = __float_as_uint(a), ub = __float_as_uint(b);
    ua += 0x7fffu + ((ua >> 16) & 1u);
    ub += 0x7fffu + ((ub >> 16) & 1u);
    return (ua >> 16) | (ub & 0xffff0000u);
}

// ---------------- count only (histogram of col) ----------------
__global__ void k_count(const int* __restrict__ col, int* __restrict__ counts) {
    int e = blockIdx.x * blockDim.x + threadIdx.x;
    if (e < NE) atomicAdd(&counts[col[e]], 1);
}

// ---------------- exclusive scan of counts ----------------
__global__ void k_scanA(const int* __restrict__ counts, int* __restrict__ offsets,
                        int* __restrict__ blockSums) {
    __shared__ int tmp[256];
    int i = blockIdx.x * 256 + threadIdx.x;
    int v = (i < NN) ? counts[i] : 0;
    tmp[threadIdx.x] = v;
    __syncthreads();
    for (int off = 1; off < 256; off <<= 1) {
        int t = (threadIdx.x >= off) ? tmp[threadIdx.x - off] : 0;
        __syncthreads();
        tmp[threadIdx.x] += t;
        __syncthreads();
    }
    if (i < NN) offsets[i] = tmp[threadIdx.x] - v;
    if (threadIdx.x == 255) blockSums[blockIdx.x] = tmp[255];
}

__global__ void k_scanB(int* __restrict__ blockSums) {
    __shared__ int tmp[256];
    int t = threadIdx.x;
    int v = (t < SCAN_BLOCKS) ? blockSums[t] : 0;
    tmp[t] = v;
    __syncthreads();
    for (int off = 1; off < 256; off <<= 1) {
        int u = (t >= off) ? tmp[t - off] : 0;
        __syncthreads();
        tmp[t] += u;
        __syncthreads();
    }
    if (t < SCAN_BLOCKS) blockSums[t] = tmp[t] - v;
}

__global__ void k_scanC(int* __restrict__ offsets, const int* __restrict__ blockSums,
                        int* __restrict__ cursor) {
    int i = blockIdx.x * 256 + threadIdx.x;
    if (i < NN) {
        int o = offsets[i] + blockSums[blockIdx.x];
        offsets[i] = o;
        cursor[i] = o;
    }
}

// ---------------- CSR fill: packed {row, ew} ----------------
__global__ void k_fill(const int* __restrict__ row, const int* __restrict__ col,
                       const float* __restrict__ ew, int* __restrict__ cursor,
                       long long* __restrict__ csr) {
    int e = blockIdx.x * blockDim.x + threadIdx.x;
    if (e < NE) {
        int r = row[e];
        float w = ew[e];
        int pos = atomicAdd(&cursor[col[e]], 1);
        long long v = (long long)(unsigned)r | ((long long)__float_as_int(w) << 32);
        __builtin_nontemporal_store(v, csr + pos);
    }
}

// ---------------- dinv from CSR segments (no atomics) ----------------
__global__ void k_dinv2(const int* __restrict__ offsets, const int* __restrict__ counts,
                        const long long* __restrict__ csr, float* __restrict__ dinv) {
    int n = blockIdx.x * blockDim.x + threadIdx.x;
    if (n >= NN) return;
    int s = offsets[n], c = counts[n];
    float d = 0.f;
    for (int j = 0; j < c; ++j)
        d += __int_as_float((int)(csr[s + j] >> 32));
    dinv[n] = rsqrtf(d + 1.0f); // +1 = self-loop weight
}

// ---------------- GEMM: C = dinv[row]*(A @ W), C in chunked bf16 [4][NN][32] --------
template <typename TIN>
__global__ __launch_bounds__(256) void k_gemm(const TIN* __restrict__ A,
                                              const float* __restrict__ W,
                                              const float* __restrict__ dinv,
                                              unsigned short* __restrict__ C) {
    __shared__ float As[64][33];
    __shared__ float Ws[32][128];
    const int row0 = blockIdx.x * 64;
    const int t = threadIdx.x;
    const int c4 = (t & 31) * 4;
    const int rg = t >> 5;
    float4 acc[8];
#pragma unroll
    for (int i = 0; i < 8; ++i) acc[i] = make_float4(0.f, 0.f, 0.f, 0.f);

    for (int k0 = 0; k0 < 128; k0 += 32) {
        if constexpr (sizeof(TIN) == 4) {
#pragma unroll
            for (int l = 0; l < 2; ++l) {
                int q = t + l * 256;
                int r = q >> 3, kk4 = (q & 7) * 4;
                int grow = row0 + r;
                float4 v = make_float4(0.f, 0.f, 0.f, 0.f);
                if (grow < NN) v = *(const float4*)((const float*)A + (size_t)grow * 128 + k0 + kk4);
                As[r][kk4] = v.x; As[r][kk4 + 1] = v.y; As[r][kk4 + 2] = v.z; As[r][kk4 + 3] = v.w;
            }
        } else {
            // bf16 A in chunked layout [4][NN][32]
            int r = t >> 2, kk8 = (t & 3) * 8;
            int grow = row0 + r;
            uint4 v = make_uint4(0u, 0u, 0u, 0u);
            if (grow < NN)
                v = *(const uint4*)((const unsigned short*)A + (size_t)(k0 >> 5) * NN * 32 +
                                    (size_t)grow * 32 + kk8);
            As[r][kk8 + 0] = bflo(v.x); As[r][kk8 + 1] = bfhi(v.x);
            As[r][kk8 + 2] = bflo(v.y); As[r][kk8 + 3] = bfhi(v.y);
            As[r][kk8 + 4] = bflo(v.z); As[r][kk8 + 5] = bfhi(v.z);
            As[r][kk8 + 6] = bflo(v.w); As[r][kk8 + 7] = bfhi(v.w);
        }
#pragma unroll
        for (int l = 0; l < 4; ++l) {
            int q = t + l * 256;
            int kk = q >> 5, cc4 = (q & 31) * 4;
            *(float4*)(&Ws[kk][cc4]) = *(const float4*)(W + (size_t)(k0 + kk) * 128 + cc4);
        }
        __syncthreads();
#pragma unroll
        for (int kk = 0; kk < 32; ++kk) {
            float4 w4 = *(const float4*)(&Ws[kk][c4]);
#pragma unroll
            for (int i = 0; i < 8; ++i) {
                float a = As[rg + 8 * i][kk];
                acc[i].x += a * w4.x;
                acc[i].y += a * w4.y;
                acc[i].z += a * w4.z;
                acc[i].w += a * w4.w;
            }
        }
        __syncthreads();
    }
#pragma unroll
    for (int i = 0; i < 8; ++i) {
        int grow = row0 + rg + 8 * i;
        if (grow < NN) {
            float di = dinv[grow];
            unsigned u0 = packbf(acc[i].x * di, acc[i].y * di);
            unsigned u1 = packbf(acc[i].z * di, acc[i].w * di);
            *(uint2*)(C + (size_t)(c4 >> 5) * NN * 32 + (size_t)grow * 32 + (c4 & 31)) =
                make_uint2(u0, u1);
        }
    }
}

// ---------------- chunked pull aggregation: one pass per 32-feat chunk -------------
// hc/outc/bias point at chunk p. Wave per node; 8 edge-groups x 8 feature-lanes.
// out[n] = relu( b + dinv[n] * ( sum_e ew_e * hs[row_e] + hs[n] ) ), bf16 out
__global__ __launch_bounds__(256) void k_agg(const unsigned short* __restrict__ hc,
                                             const int* __restrict__ offsets,
                                             const int* __restrict__ counts,
                                             const long long* __restrict__ csr,
                                             const float* __restrict__ dinv,
                                             const float* __restrict__ bias,
                                             unsigned short* __restrict__ outc) {
    const int node = blockIdx.x * 4 + (threadIdx.x >> 6);
    if (node >= NN) return;
    const int lane = threadIdx.x & 63;
    const int eg = lane >> 3;   // edge group 0..7
    const int fl = lane & 7;    // feature lane: owns feats [fl*4, fl*4+4) of this chunk

    const int start = offsets[node];
    const int cnt = counts[node];
    const long long* ep = csr + start;
    const uint2* hb = (const uint2*)hc; // 8 uint2 per 32-feat row

    float a0 = 0.f, a1 = 0.f, a2 = 0.f, a3 = 0.f;
    auto fma4 = [&](uint2 v, float w) {
        a0 += bflo(v.x) * w; a1 += bfhi(v.x) * w;
        a2 += bflo(v.y) * w; a3 += bfhi(v.y) * w;
    };

    const int n16 = cnt >> 4;
    for (int i = 0; i < n16; ++i) {
        const int base = i * 16 + eg;
        long long l0 = __builtin_nontemporal_load(ep + base);
        long long l1 = __builtin_nontemporal_load(ep + base + 8);
        uint2 v0 = hb[(size_t)(int)l0 * 8 + fl];
        uint2 v1 = hb[(size_t)(int)l1 * 8 + fl];
        fma4(v0, __int_as_float((int)(l0 >> 32)));
        fma4(v1, __int_as_float((int)(l1 >> 32)));
    }
    for (int jj = n16 * 16; jj < cnt; jj += 8) {
        int idx = jj + eg;
        bool valid = idx < cnt;
        long long l = __builtin_nontemporal_load(ep + (valid ? idx : cnt - 1));
        float w = valid ? __int_as_float((int)(l >> 32)) : 0.f;
        uint2 v = hb[(size_t)(int)l * 8 + fl];
        fma4(v, w);
    }

    // combine the 8 edge-groups
    a0 += __shfl_xor(a0, 8); a0 += __shfl_xor(a0, 16); a0 += __shfl_xor(a0, 32);
    a1 += __shfl_xor(a1, 8); a1 += __shfl_xor(a1, 16); a1 += __shfl_xor(a1, 32);
    a2 += __shfl_xor(a2, 8); a2 += __shfl_xor(a2, 16); a2 += __shfl_xor(a2, 32);
    a3 += __shfl_xor(a3, 8); a3 += __shfl_xor(a3, 16); a3 += __shfl_xor(a3, 32);

    if (eg == 0) {
        uint2 sv = hb[(size_t)node * 8 + fl];
        fma4(sv, 1.0f);                        // self-loop term: + hs[node]
        float di = dinv[node];
        float4 b4 = *(const float4*)(bias + fl * 4);
        a0 = fmaxf(di * a0 + b4.x, 0.f);
        a1 = fmaxf(di * a1 + b4.y, 0.f);
        a2 = fmaxf(di * a2 + b4.z, 0.f);
        a3 = fmaxf(di * a3 + b4.w, 0.f);
        *(uint2*)(outc + (size_t)node * 32 + fl * 4) = make_uint2(packbf(a0, a1), packbf(a2, a3));
    }
}

// ---------------- segmented pooling (batch sorted, chunked h3) --------------------
__global__ __launch_bounds__(256) void k_pool(const unsigned short* __restrict__ h3,
                                              const int* __restrict__ batch,
                                              float* __restrict__ pooled) {
    __shared__ float sm[256];
    const int g = blockIdx.x;
    const int f = threadIdx.x & 127;
    const int half = threadIdx.x >> 7;
    const unsigned short* hp = h3 + (size_t)(f >> 5) * NN * 32 + (f & 31);
    // lower_bound(g), lower_bound(g+1)
    int lo = 0, hi = NN;
    while (lo < hi) { int m = (lo + hi) >> 1; if (batch[m] < g) lo = m + 1; else hi = m; }
    int s0 = lo;
    hi = NN;
    while (lo < hi) { int m = (lo + hi) >> 1; if (batch[m] < g + 1) lo = m + 1; else hi = m; }
    int e0 = lo;

    float s = 0.f;
    int n = s0 + half;
    for (; n + 8 <= e0; n += 8) {
        s += bfs(hp[(size_t)n * 32]);
        s += bfs(hp[(size_t)(n + 2) * 32]);
        s += bfs(hp[(size_t)(n + 4) * 32]);
        s += bfs(hp[(size_t)(n + 6) * 32]);
    }
    for (; n < e0; n += 2) s += bfs(hp[(size_t)n * 32]);

    sm[threadIdx.x] = s;
    __syncthreads();
    if (half == 0) pooled[(size_t)g * 128 + f] = sm[threadIdx.x] + sm[threadIdx.x + 128];
}

// ---------------- FC + log_softmax: one wave per graph ----------------
__global__ __launch_bounds__(64) void k_fc(const float* __restrict__ pooled,
                                           const float* __restrict__ Wfc,
                                           const float* __restrict__ bfc,
                                           float* __restrict__ out) {
    const int g = blockIdx.x;
    const int lane = threadIdx.x;
    float p0 = pooled[(size_t)g * 128 + lane];
    float p1 = pooled[(size_t)g * 128 + 64 + lane];
    float logits[NC];
#pragma unroll
    for (int c = 0; c < NC; ++c) {
        float v = p0 * Wfc[lane * NC + c] + p1 * Wfc[(64 + lane) * NC + c];
#pragma unroll
        for (int off = 32; off > 0; off >>= 1) v += __shfl_down(v, off);
        logits[c] = v;
    }
    if (lane == 0) {
        float mx = -1e30f;
#pragma unroll
        for (int c = 0; c < NC; ++c) { logits[c] += bfc[c]; mx = fmaxf(mx, logits[c]); }
        float s = 0.f;
#pragma unroll
        for (int c = 0; c < NC; ++c) s += expf(logits[c] - mx);
        float lse = mx + logf(s);
#pragma unroll
        for (int c = 0; c < NC; ++c) out[(size_t)g * NC + c] = logits[c] - lse;
    }
}

extern "C" void kernel_launch(void* const* d_in, const int* in_sizes, int n_in,
                              void* d_out, int out_size, void* d_ws, size_t ws_size,
                              hipStream_t stream) {
    const float* x         = (const float*)d_in[0];
    const int*   edge_index= (const int*)d_in[1];
    const int*   batch     = (const int*)d_in[2];
    const float* edge_mask = (const float*)d_in[3];
    const float* W1        = (const float*)d_in[4];
    const float* b1        = (const float*)d_in[5];
    const float* W2        = (const float*)d_in[6];
    const float* b2        = (const float*)d_in[7];
    const float* Wfc       = (const float*)d_in[8];
    const float* bfc       = (const float*)d_in[9];
    float* out = (float*)d_out;

    const int* row = edge_index;        // edge_index[0]
    const int* col = edge_index + NE;   // edge_index[1]

    char* ws = (char*)d_ws;
    size_t off = 0;
    auto alloc = [&](size_t bytes) -> void* {
        off = (off + 255) & ~(size_t)255;
        void* p = ws + off;
        off += bytes;
        return p;
    };
    int*   counts   = (int*)  alloc((size_t)NN * 4);
    int*   offsets  = (int*)  alloc((size_t)NN * 4);
    int*   cursor   = (int*)  alloc((size_t)NN * 4);
    int*   blockSums= (int*)  alloc(256 * 4);
    float* dinv     = (float*)alloc((size_t)NN * 4);
    long long* csr  = (long long*)alloc((size_t)NE * 8);
    unsigned short* hs1 = (unsigned short*)alloc((size_t)NN * FEAT * 2); // chunked bf16
    unsigned short* h2  = (unsigned short*)alloc((size_t)NN * FEAT * 2); // chunked bf16
    unsigned short* h3  = (unsigned short*)alloc((size_t)NN * FEAT * 2); // chunked bf16
    float* pooled   = (float*)alloc((size_t)NG * FEAT * 4);

    hipMemsetAsync(counts, 0, (size_t)NN * 4, stream);

    k_count<<<(NE + 255) / 256, 256, 0, stream>>>(col, counts);
    k_scanA<<<SCAN_BLOCKS, 256, 0, stream>>>(counts, offsets, blockSums);
    k_scanB<<<1, 256, 0, stream>>>(blockSums);
    k_scanC<<<SCAN_BLOCKS, 256, 0, stream>>>(offsets, blockSums, cursor);
    k_fill<<<(NE + 255) / 256, 256, 0, stream>>>(row, col, edge_mask, cursor, csr);
    k_dinv2<<<(NN + 255) / 256, 256, 0, stream>>>(offsets, counts, csr, dinv);

    const size_t CH = (size_t)NN * 32; // elements per chunk

    // layer 1: hs1 = dinv * (x @ W1); h2 = relu(b1 + dinv*(sum ew*hs1 + hs1))
    k_gemm<float><<<(NN + 63) / 64, 256, 0, stream>>>(x, W1, dinv, hs1);
    for (int p = 0; p < 4; ++p)
        k_agg<<<(NN + 3) / 4, 256, 0, stream>>>(hs1 + p * CH, offsets, counts, csr, dinv,
                                                b1 + p * 32, h2 + p * CH);
    // layer 2
    k_gemm<unsigned short><<<(NN + 63) / 64, 256, 0, stream>>>(h2, W2, dinv, hs1);
    for (int p = 0; p < 4; ++p)
        k_agg<<<(NN + 3) / 4, 256, 0, stream>>>(hs1 + p * CH, offsets, counts, csr, dinv,
                                                b2 + p * 32, h3 + p * CH);
    // pool + FC
    k_pool<<<NG, 256, 0, stream>>>(h3, batch, pooled);
    k_fc<<<NG, 64, 0, stream>>>(pooled, Wfc, bfc, out);
}

// Round 7
// 469.003 us; speedup vs baseline: 1.4500x; 1.4500x over previous
//
#include <hip/hip_runtime.h>
#include <hip/hip_bf16.h>

#define NN 50000
#define NE 1600000
#define FEAT 128
#define NG 128
#define NC 10

constexpr int SCAN_BLOCKS = (NN + 255) / 256; // 196

typedef unsigned int u32x4 __attribute__((ext_vector_type(4)));

// ---------------- bf16 helpers (manual, RNE) ----------------
__device__ __forceinline__ float bflo(unsigned u) { return __uint_as_float(u << 16); }
__device__ __forceinline__ float bfhi(unsigned u) { return __uint_as_float(u & 0xffff0000u); }
__device__ __forceinline__ float bfs(unsigned short u) { return __uint_as_float(((unsigned)u) << 16); }
__device__ __forceinline__ unsigned packbf(float a, float b) {
    unsigned ua = __float_as_uint(a), ub = __float_as_uint(b);
    ua += 0x7fffu + ((ua >> 16) & 1u);
    ub += 0x7fffu + ((ub >> 16) & 1u);
    return (ua >> 16) | (ub & 0xffff0000u);
}

// ---------------- rank pass: counts histogram + within-node rank ----------------
__global__ void k_rank(const int* __restrict__ col, int* __restrict__ counts,
                       int* __restrict__ rank) {
    int e = blockIdx.x * blockDim.x + threadIdx.x;
    if (e < NE) rank[e] = atomicAdd(&counts[col[e]], 1);
}

// ---------------- exclusive scan of counts ----------------
__global__ void k_scanA(const int* __restrict__ counts, int* __restrict__ offsets,
                        int* __restrict__ blockSums) {
    __shared__ int tmp[256];
    int i = blockIdx.x * 256 + threadIdx.x;
    int v = (i < NN) ? counts[i] : 0;
    tmp[threadIdx.x] = v;
    __syncthreads();
    for (int off = 1; off < 256; off <<= 1) {
        int t = (threadIdx.x >= off) ? tmp[threadIdx.x - off] : 0;
        __syncthreads();
        tmp[threadIdx.x] += t;
        __syncthreads();
    }
    if (i < NN) offsets[i] = tmp[threadIdx.x] - v;
    if (threadIdx.x == 255) blockSums[blockIdx.x] = tmp[255];
}

__global__ void k_scanB(int* __restrict__ blockSums) {
    __shared__ int tmp[256];
    int t = threadIdx.x;
    int v = (t < SCAN_BLOCKS) ? blockSums[t] : 0;
    tmp[t] = v;
    __syncthreads();
    for (int off = 1; off < 256; off <<= 1) {
        int u = (t >= off) ? tmp[t - off] : 0;
        __syncthreads();
        tmp[t] += u;
        __syncthreads();
    }
    if (t < SCAN_BLOCKS) blockSums[t] = tmp[t] - v;
}

__global__ void k_scanC(int* __restrict__ offsets, const int* __restrict__ blockSums) {
    int i = blockIdx.x * 256 + threadIdx.x;
    if (i < NN) offsets[i] += blockSums[blockIdx.x];
}

// ---------------- CSR fill: NO atomics (pos = offsets[col] + rank) ----------------
__global__ void k_fill(const int* __restrict__ row, const int* __restrict__ col,
                       const float* __restrict__ ew, const int* __restrict__ rank,
                       const int* __restrict__ offsets, long long* __restrict__ csr) {
    int e = blockIdx.x * blockDim.x + threadIdx.x;
    if (e < NE) {
        int pos = offsets[col[e]] + rank[e];
        long long v = (long long)(unsigned)row[e] | ((long long)__float_as_int(ew[e]) << 32);
        __builtin_nontemporal_store(v, csr + pos);
    }
}

// ---------------- dinv from CSR segments (no atomics) ----------------
__global__ void k_dinv2(const int* __restrict__ offsets, const int* __restrict__ counts,
                        const long long* __restrict__ csr, float* __restrict__ dinv) {
    int n = blockIdx.x * blockDim.x + threadIdx.x;
    if (n >= NN) return;
    int s = offsets[n], c = counts[n];
    float d = 0.f;
    for (int j = 0; j < c; ++j)
        d += __int_as_float((int)(csr[s + j] >> 32));
    dinv[n] = rsqrtf(d + 1.0f); // +1 = self-loop weight
}

// ---------------- GEMM: C_bf16[NN x 128] = dinv[row] * (A[NN x 128] @ W[128 x 128]) ----
template <typename TIN>
__global__ __launch_bounds__(256) void k_gemm(const TIN* __restrict__ A,
                                              const float* __restrict__ W,
                                              const float* __restrict__ dinv,
                                              unsigned short* __restrict__ C) {
    __shared__ float As[64][33];
    __shared__ float Ws[32][128];
    const int row0 = blockIdx.x * 64;
    const int t = threadIdx.x;
    const int c4 = (t & 31) * 4;
    const int rg = t >> 5;
    float4 acc[8];
#pragma unroll
    for (int i = 0; i < 8; ++i) acc[i] = make_float4(0.f, 0.f, 0.f, 0.f);

    for (int k0 = 0; k0 < 128; k0 += 32) {
        if constexpr (sizeof(TIN) == 4) {
#pragma unroll
            for (int l = 0; l < 2; ++l) {
                int q = t + l * 256;
                int r = q >> 3, kk4 = (q & 7) * 4;
                int grow = row0 + r;
                float4 v = make_float4(0.f, 0.f, 0.f, 0.f);
                if (grow < NN) v = *(const float4*)((const float*)A + (size_t)grow * 128 + k0 + kk4);
                As[r][kk4] = v.x; As[r][kk4 + 1] = v.y; As[r][kk4 + 2] = v.z; As[r][kk4 + 3] = v.w;
            }
        } else {
            int r = t >> 2, kk8 = (t & 3) * 8;
            int grow = row0 + r;
            uint4 v = make_uint4(0u, 0u, 0u, 0u);
            if (grow < NN)
                v = *(const uint4*)((const unsigned short*)A + (size_t)grow * 128 + k0 + kk8);
            As[r][kk8 + 0] = bflo(v.x); As[r][kk8 + 1] = bfhi(v.x);
            As[r][kk8 + 2] = bflo(v.y); As[r][kk8 + 3] = bfhi(v.y);
            As[r][kk8 + 4] = bflo(v.z); As[r][kk8 + 5] = bfhi(v.z);
            As[r][kk8 + 6] = bflo(v.w); As[r][kk8 + 7] = bfhi(v.w);
        }
#pragma unroll
        for (int l = 0; l < 4; ++l) {
            int q = t + l * 256;
            int kk = q >> 5, cc4 = (q & 31) * 4;
            *(float4*)(&Ws[kk][cc4]) = *(const float4*)(W + (size_t)(k0 + kk) * 128 + cc4);
        }
        __syncthreads();
#pragma unroll
        for (int kk = 0; kk < 32; ++kk) {
            float4 w4 = *(const float4*)(&Ws[kk][c4]);
#pragma unroll
            for (int i = 0; i < 8; ++i) {
                float a = As[rg + 8 * i][kk];
                acc[i].x += a * w4.x;
                acc[i].y += a * w4.y;
                acc[i].z += a * w4.z;
                acc[i].w += a * w4.w;
            }
        }
        __syncthreads();
    }
#pragma unroll
    for (int i = 0; i < 8; ++i) {
        int grow = row0 + rg + 8 * i;
        if (grow < NN) {
            float di = dinv[grow];
            unsigned u0 = packbf(acc[i].x * di, acc[i].y * di);
            unsigned u1 = packbf(acc[i].z * di, acc[i].w * di);
            *(uint2*)(C + (size_t)grow * 128 + c4) = make_uint2(u0, u1);
        }
    }
}

// ---------------- pull aggregation: quarter-wave (16 lanes = one 256B row) ----------
// out[n] = relu( b + dinv[n] * ( sum_e ew_e * hs[row_e] + hs[n] ) ), bf16 out
__global__ __launch_bounds__(256) void k_agg(const unsigned short* __restrict__ hs,
                                             const int* __restrict__ offsets,
                                             const int* __restrict__ counts,
                                             const long long* __restrict__ csr,
                                             const float* __restrict__ dinv,
                                             const float* __restrict__ bias,
                                             unsigned short* __restrict__ outb) {
    const int node = blockIdx.x * 4 + (threadIdx.x >> 6);
    if (node >= NN) return;
    const int lane = threadIdx.x & 63;
    const int qg = lane >> 4;   // quarter-group: which edge of 4
    const int fl = lane & 15;   // feature lane: owns feats [fl*8, fl*8+8)

    const int start = offsets[node];
    const int cnt = counts[node];
    const long long* ep = csr + start;
    const uint4* hb = (const uint4*)hs;

    float a0 = 0.f, a1 = 0.f, a2 = 0.f, a3 = 0.f;
    float a4 = 0.f, a5 = 0.f, a6 = 0.f, a7 = 0.f;

    auto fma8 = [&](uint4 v, float w) {
        a0 += bflo(v.x) * w; a1 += bfhi(v.x) * w;
        a2 += bflo(v.y) * w; a3 += bfhi(v.y) * w;
        a4 += bflo(v.z) * w; a5 += bfhi(v.z) * w;
        a6 += bflo(v.w) * w; a7 += bfhi(v.w) * w;
    };

    const int n16 = cnt >> 4;
    for (int i = 0; i < n16; ++i) {
        const int base = i * 16 + qg;
        long long l0 = __builtin_nontemporal_load(ep + base);
        long long l1 = __builtin_nontemporal_load(ep + base + 4);
        long long l2 = __builtin_nontemporal_load(ep + base + 8);
        long long l3 = __builtin_nontemporal_load(ep + base + 12);
        uint4 v0 = hb[(size_t)(int)l0 * 16 + fl];
        uint4 v1 = hb[(size_t)(int)l1 * 16 + fl];
        uint4 v2 = hb[(size_t)(int)l2 * 16 + fl];
        uint4 v3 = hb[(size_t)(int)l3 * 16 + fl];
        fma8(v0, __int_as_float((int)(l0 >> 32)));
        fma8(v1, __int_as_float((int)(l1 >> 32)));
        fma8(v2, __int_as_float((int)(l2 >> 32)));
        fma8(v3, __int_as_float((int)(l3 >> 32)));
    }
    for (int jj = n16 * 16; jj < cnt; jj += 4) {
        int idx = jj + qg;
        bool valid = idx < cnt;
        long long l = __builtin_nontemporal_load(ep + (valid ? idx : cnt - 1));
        float w = valid ? __int_as_float((int)(l >> 32)) : 0.f;
        uint4 v = hb[(size_t)(int)l * 16 + fl];
        fma8(v, w);
    }

    // combine the 4 quarter-groups
    a0 += __shfl_xor(a0, 16); a0 += __shfl_xor(a0, 32);
    a1 += __shfl_xor(a1, 16); a1 += __shfl_xor(a1, 32);
    a2 += __shfl_xor(a2, 16); a2 += __shfl_xor(a2, 32);
    a3 += __shfl_xor(a3, 16); a3 += __shfl_xor(a3, 32);
    a4 += __shfl_xor(a4, 16); a4 += __shfl_xor(a4, 32);
    a5 += __shfl_xor(a5, 16); a5 += __shfl_xor(a5, 32);
    a6 += __shfl_xor(a6, 16); a6 += __shfl_xor(a6, 32);
    a7 += __shfl_xor(a7, 16); a7 += __shfl_xor(a7, 32);

    if (qg == 0) {
        uint4 sv = hb[(size_t)node * 16 + fl];
        fma8(sv, 1.0f);                        // self-loop term: + hs[node]
        float di = dinv[node];
        float4 b0 = *(const float4*)(bias + fl * 8);
        float4 b1 = *(const float4*)(bias + fl * 8 + 4);
        a0 = fmaxf(di * a0 + b0.x, 0.f);
        a1 = fmaxf(di * a1 + b0.y, 0.f);
        a2 = fmaxf(di * a2 + b0.z, 0.f);
        a3 = fmaxf(di * a3 + b0.w, 0.f);
        a4 = fmaxf(di * a4 + b1.x, 0.f);
        a5 = fmaxf(di * a5 + b1.y, 0.f);
        a6 = fmaxf(di * a6 + b1.z, 0.f);
        a7 = fmaxf(di * a7 + b1.w, 0.f);
        u32x4 o;
        o.x = packbf(a0, a1); o.y = packbf(a2, a3);
        o.z = packbf(a4, a5); o.w = packbf(a6, a7);
        __builtin_nontemporal_store(o, (u32x4*)(outb + (size_t)node * 128 + fl * 8));
    }
}

// ---------------- segmented pooling (batch sorted): one block per graph --------------
__global__ __launch_bounds__(256) void k_pool(const unsigned short* __restrict__ h3,
                                              const int* __restrict__ batch,
                                              float* __restrict__ pooled) {
    __shared__ float sm[256];
    const int g = blockIdx.x;
    const int f = threadIdx.x & 127;
    const int half = threadIdx.x >> 7;
    // lower_bound(g), lower_bound(g+1)
    int lo = 0, hi = NN;
    while (lo < hi) { int m = (lo + hi) >> 1; if (batch[m] < g) lo = m + 1; else hi = m; }
    int s0 = lo;
    hi = NN;
    while (lo < hi) { int m = (lo + hi) >> 1; if (batch[m] < g + 1) lo = m + 1; else hi = m; }
    int e0 = lo;

    float s = 0.f;
    int n = s0 + half;
    for (; n + 8 <= e0; n += 8) {
        s += bfs(h3[(size_t)n * 128 + f]);
        s += bfs(h3[(size_t)(n + 2) * 128 + f]);
        s += bfs(h3[(size_t)(n + 4) * 128 + f]);
        s += bfs(h3[(size_t)(n + 6) * 128 + f]);
    }
    for (; n < e0; n += 2) s += bfs(h3[(size_t)n * 128 + f]);

    sm[threadIdx.x] = s;
    __syncthreads();
    if (half == 0) pooled[(size_t)g * 128 + f] = sm[threadIdx.x] + sm[threadIdx.x + 128];
}

// ---------------- FC + log_softmax: one wave per graph ----------------
__global__ __launch_bounds__(64) void k_fc(const float* __restrict__ pooled,
                                           const float* __restrict__ Wfc,
                                           const float* __restrict__ bfc,
                                           float* __restrict__ out) {
    const int g = blockIdx.x;
    const int lane = threadIdx.x;
    float p0 = pooled[(size_t)g * 128 + lane];
    float p1 = pooled[(size_t)g * 128 + 64 + lane];
    float logits[NC];
#pragma unroll
    for (int c = 0; c < NC; ++c) {
        float v = p0 * Wfc[lane * NC + c] + p1 * Wfc[(64 + lane) * NC + c];
#pragma unroll
        for (int off = 32; off > 0; off >>= 1) v += __shfl_down(v, off);
        logits[c] = v;
    }
    if (lane == 0) {
        float mx = -1e30f;
#pragma unroll
        for (int c = 0; c < NC; ++c) { logits[c] += bfc[c]; mx = fmaxf(mx, logits[c]); }
        float s = 0.f;
#pragma unroll
        for (int c = 0; c < NC; ++c) s += expf(logits[c] - mx);
        float lse = mx + logf(s);
#pragma unroll
        for (int c = 0; c < NC; ++c) out[(size_t)g * NC + c] = logits[c] - lse;
    }
}

extern "C" void kernel_launch(void* const* d_in, const int* in_sizes, int n_in,
                              void* d_out, int out_size, void* d_ws, size_t ws_size,
                              hipStream_t stream) {
    const float* x         = (const float*)d_in[0];
    const int*   edge_index= (const int*)d_in[1];
    const int*   batch     = (const int*)d_in[2];
    const float* edge_mask = (const float*)d_in[3];
    const float* W1        = (const float*)d_in[4];
    const float* b1        = (const float*)d_in[5];
    const float* W2        = (const float*)d_in[6];
    const float* b2        = (const float*)d_in[7];
    const float* Wfc       = (const float*)d_in[8];
    const float* bfc       = (const float*)d_in[9];
    float* out = (float*)d_out;

    const int* row = edge_index;        // edge_index[0]
    const int* col = edge_index + NE;   // edge_index[1]

    char* ws = (char*)d_ws;
    size_t off = 0;
    auto alloc = [&](size_t bytes) -> void* {
        off = (off + 255) & ~(size_t)255;
        void* p = ws + off;
        off += bytes;
        return p;
    };
    int*   counts   = (int*)  alloc((size_t)NN * 4);
    int*   offsets  = (int*)  alloc((size_t)NN * 4);
    int*   blockSums= (int*)  alloc(256 * 4);
    float* dinv     = (float*)alloc((size_t)NN * 4);
    int*   rank     = (int*)  alloc((size_t)NE * 4);
    long long* csr  = (long long*)alloc((size_t)NE * 8);
    unsigned short* hs1 = (unsigned short*)alloc((size_t)NN * FEAT * 2); // scaled bf16
    unsigned short* h2  = (unsigned short*)alloc((size_t)NN * FEAT * 2);
    unsigned short* h3  = (unsigned short*)alloc((size_t)NN * FEAT * 2);
    float* pooled   = (float*)alloc((size_t)NG * FEAT * 4);

    hipMemsetAsync(counts, 0, (size_t)NN * 4, stream);

    k_rank<<<(NE + 255) / 256, 256, 0, stream>>>(col, counts, rank);
    k_scanA<<<SCAN_BLOCKS, 256, 0, stream>>>(counts, offsets, blockSums);
    k_scanB<<<1, 256, 0, stream>>>(blockSums);
    k_scanC<<<SCAN_BLOCKS, 256, 0, stream>>>(offsets, blockSums);
    k_fill<<<(NE + 255) / 256, 256, 0, stream>>>(row, col, edge_mask, rank, offsets, csr);
    k_dinv2<<<(NN + 255) / 256, 256, 0, stream>>>(offsets, counts, csr, dinv);

    // layer 1: hs1 = dinv * (x @ W1); h2 = relu(b1 + dinv*(sum ew*hs1 + hs1))
    k_gemm<float><<<(NN + 63) / 64, 256, 0, stream>>>(x, W1, dinv, hs1);
    k_agg<<<(NN + 3) / 4, 256, 0, stream>>>(hs1, offsets, counts, csr, dinv, b1, h2);
    // layer 2
    k_gemm<unsigned short><<<(NN + 63) / 64, 256, 0, stream>>>(h2, W2, dinv, hs1);
    k_agg<<<(NN + 3) / 4, 256, 0, stream>>>(hs1, offsets, counts, csr, dinv, b2, h3);
    // pool + FC
    k_pool<<<NG, 256, 0, stream>>>(h3, batch, pooled);
    k_fc<<<NG, 64, 0, stream>>>(pooled, Wfc, bfc, out);
}

// Round 8
// 439.214 us; speedup vs baseline: 1.5483x; 1.0678x over previous
//
#include <hip/hip_runtime.h>
#include <hip/hip_bf16.h>

#define NN 50000
#define NE 1600000
#define FEAT 128
#define NG 128
#define NC 10

constexpr int SCAN_BLOCKS = (NN + 255) / 256; // 196

typedef unsigned int u32x4 __attribute__((ext_vector_type(4)));
typedef short bf16x8 __attribute__((ext_vector_type(8)));
typedef float f32x4 __attribute__((ext_vector_type(4)));

// ---------------- bf16 helpers (manual, RNE) ----------------
__device__ __forceinline__ float bflo(unsigned u) { return __uint_as_float(u << 16); }
__device__ __forceinline__ float bfhi(unsigned u) { return __uint_as_float(u & 0xffff0000u); }
__device__ __forceinline__ float bfs(unsigned short u) { return __uint_as_float(((unsigned)u) << 16); }
__device__ __forceinline__ unsigned packbf(float a, float b) {
    unsigned ua = __float_as_uint(a), ub = __float_as_uint(b);
    ua += 0x7fffu + ((ua >> 16) & 1u);
    ub += 0x7fffu + ((ub >> 16) & 1u);
    return (ua >> 16) | (ub & 0xffff0000u);
}
__device__ __forceinline__ unsigned short bf1(float a) {
    unsigned ua = __float_as_uint(a);
    ua += 0x7fffu + ((ua >> 16) & 1u);
    return (unsigned short)(ua >> 16);
}

// ---------------- rank pass: counts histogram + within-node rank ----------------
__global__ void k_rank(const int* __restrict__ col, int* __restrict__ counts,
                       int* __restrict__ rank) {
    int e = blockIdx.x * blockDim.x + threadIdx.x;
    if (e < NE) rank[e] = atomicAdd(&counts[col[e]], 1);
}

// ---------------- exclusive scan of counts ----------------
__global__ void k_scanA(const int* __restrict__ counts, int* __restrict__ offsets,
                        int* __restrict__ blockSums) {
    __shared__ int tmp[256];
    int i = blockIdx.x * 256 + threadIdx.x;
    int v = (i < NN) ? counts[i] : 0;
    tmp[threadIdx.x] = v;
    __syncthreads();
    for (int off = 1; off < 256; off <<= 1) {
        int t = (threadIdx.x >= off) ? tmp[threadIdx.x - off] : 0;
        __syncthreads();
        tmp[threadIdx.x] += t;
        __syncthreads();
    }
    if (i < NN) offsets[i] = tmp[threadIdx.x] - v;
    if (threadIdx.x == 255) blockSums[blockIdx.x] = tmp[255];
}

__global__ void k_scanB(int* __restrict__ blockSums) {
    __shared__ int tmp[256];
    int t = threadIdx.x;
    int v = (t < SCAN_BLOCKS) ? blockSums[t] : 0;
    tmp[t] = v;
    __syncthreads();
    for (int off = 1; off < 256; off <<= 1) {
        int u = (t >= off) ? tmp[t - off] : 0;
        __syncthreads();
        tmp[t] += u;
        __syncthreads();
    }
    if (t < SCAN_BLOCKS) blockSums[t] = tmp[t] - v;
}

__global__ void k_scanC(int* __restrict__ offsets, const int* __restrict__ blockSums) {
    int i = blockIdx.x * 256 + threadIdx.x;
    if (i < NN) offsets[i] += blockSums[blockIdx.x];
}

// ---------------- CSR fill: NO atomics (pos = offsets[col] + rank) ----------------
__global__ void k_fill(const int* __restrict__ row, const int* __restrict__ col,
                       const float* __restrict__ ew, const int* __restrict__ rank,
                       const int* __restrict__ offsets, long long* __restrict__ csr) {
    int e = blockIdx.x * blockDim.x + threadIdx.x;
    if (e < NE) {
        int pos = offsets[col[e]] + rank[e];
        long long v = (long long)(unsigned)row[e] | ((long long)__float_as_int(ew[e]) << 32);
        __builtin_nontemporal_store(v, csr + pos);
    }
}

// ---------------- dinv from CSR segments (no atomics) ----------------
__global__ void k_dinv2(const int* __restrict__ offsets, const int* __restrict__ counts,
                        const long long* __restrict__ csr, float* __restrict__ dinv) {
    int n = blockIdx.x * blockDim.x + threadIdx.x;
    if (n >= NN) return;
    int s = offsets[n], c = counts[n];
    float d = 0.f;
    for (int j = 0; j < c; ++j)
        d += __int_as_float((int)(csr[s + j] >> 32));
    dinv[n] = rsqrtf(d + 1.0f); // +1 = self-loop weight
}

// ---------------- x -> bf16 cast (8 elems/thread) ----------------
__global__ void k_cast(const float* __restrict__ x, unsigned short* __restrict__ xb) {
    size_t i = (size_t)(blockIdx.x * blockDim.x + threadIdx.x) * 8;
    const float4* p = (const float4*)(x + i);
    float4 v0 = p[0], v1 = p[1];
    u32x4 o;
    o.x = packbf(v0.x, v0.y); o.y = packbf(v0.z, v0.w);
    o.z = packbf(v1.x, v1.y); o.w = packbf(v1.z, v1.w);
    *(u32x4*)(xb + i) = o;
}

// ---------------- W[k][n] f32 -> Wt[n][k] bf16 ----------------
__global__ void k_prepW(const float* __restrict__ W, unsigned short* __restrict__ Wt) {
    int idx = blockIdx.x * 256 + threadIdx.x; // 16384 threads
    int k = idx >> 7, n = idx & 127;
    Wt[n * 128 + k] = bf1(W[idx]);
}

// ---------------- MFMA GEMM: C_bf16 = dinv[row] * (A_bf16[NN x 128] @ W[128 x 128]) ----
// A row-major bf16, Wt = W^T row-major bf16 [n][k]. No LDS; W frags from L1/L2.
// Per wave: 16 rows x 128 cols. mfma_f32_16x16x32_bf16:
//   A frag: row = lane&15, k = (lane>>4)*8 + j   (k-perm consistent A/B cancels)
//   D: col = lane&15, row = (lane>>4)*4 + reg    (m89-verified)
__global__ __launch_bounds__(256) void k_gemm_mfma(const unsigned short* __restrict__ A,
                                                   const unsigned short* __restrict__ Wt,
                                                   const float* __restrict__ dinv,
                                                   unsigned short* __restrict__ C) {
    const int t = threadIdx.x;
    const int wid = t >> 6;
    const int lane = t & 63;
    const int row0 = blockIdx.x * 64 + wid * 16;
    const int l15 = lane & 15;
    const int kg = lane >> 4; // 0..3

    int arow = row0 + l15;
    if (arow >= NN) arow = NN - 1; // clamp; stores guarded
    const unsigned short* ap = A + (size_t)arow * 128 + kg * 8;
    bf16x8 a[4];
#pragma unroll
    for (int ks = 0; ks < 4; ++ks)
        a[ks] = *(const bf16x8*)(ap + ks * 32);

    f32x4 acc[8];
#pragma unroll
    for (int ct = 0; ct < 8; ++ct) acc[ct] = (f32x4){0.f, 0.f, 0.f, 0.f};

#pragma unroll
    for (int ct = 0; ct < 8; ++ct) {
        const unsigned short* bp = Wt + (size_t)(ct * 16 + l15) * 128 + kg * 8;
#pragma unroll
        for (int ks = 0; ks < 4; ++ks) {
            bf16x8 b = *(const bf16x8*)(bp + ks * 32);
            acc[ct] = __builtin_amdgcn_mfma_f32_16x16x32_bf16(a[ks], b, acc[ct], 0, 0, 0);
        }
    }

    const int drow0 = row0 + kg * 4;
    float di[4];
#pragma unroll
    for (int r = 0; r < 4; ++r)
        di[r] = (drow0 + r < NN) ? dinv[drow0 + r] : 0.f;
#pragma unroll
    for (int ct = 0; ct < 8; ++ct) {
#pragma unroll
        for (int r = 0; r < 4; ++r) {
            int grow = drow0 + r;
            if (grow < NN)
                C[(size_t)grow * 128 + ct * 16 + l15] = bf1(acc[ct][r] * di[r]);
        }
    }
}

// ---------------- pull aggregation: quarter-wave (16 lanes = one 256B row) ----------
// out[n] = relu( b + dinv[n] * ( sum_e ew_e * hs[row_e] + hs[n] ) ), bf16 out
__global__ __launch_bounds__(256) void k_agg(const unsigned short* __restrict__ hs,
                                             const int* __restrict__ offsets,
                                             const int* __restrict__ counts,
                                             const long long* __restrict__ csr,
                                             const float* __restrict__ dinv,
                                             const float* __restrict__ bias,
                                             unsigned short* __restrict__ outb) {
    const int node = blockIdx.x * 4 + (threadIdx.x >> 6);
    if (node >= NN) return;
    const int lane = threadIdx.x & 63;
    const int qg = lane >> 4;   // quarter-group: which edge of 4
    const int fl = lane & 15;   // feature lane: owns feats [fl*8, fl*8+8)

    const int start = offsets[node];
    const int cnt = counts[node];
    const long long* ep = csr + start;
    const uint4* hb = (const uint4*)hs;

    float a0 = 0.f, a1 = 0.f, a2 = 0.f, a3 = 0.f;
    float a4 = 0.f, a5 = 0.f, a6 = 0.f, a7 = 0.f;

    auto fma8 = [&](uint4 v, float w) {
        a0 += bflo(v.x) * w; a1 += bfhi(v.x) * w;
        a2 += bflo(v.y) * w; a3 += bfhi(v.y) * w;
        a4 += bflo(v.z) * w; a5 += bfhi(v.z) * w;
        a6 += bflo(v.w) * w; a7 += bfhi(v.w) * w;
    };

    const int n16 = cnt >> 4;
    for (int i = 0; i < n16; ++i) {
        const int base = i * 16 + qg;
        long long l0 = __builtin_nontemporal_load(ep + base);
        long long l1 = __builtin_nontemporal_load(ep + base + 4);
        long long l2 = __builtin_nontemporal_load(ep + base + 8);
        long long l3 = __builtin_nontemporal_load(ep + base + 12);
        uint4 v0 = hb[(size_t)(int)l0 * 16 + fl];
        uint4 v1 = hb[(size_t)(int)l1 * 16 + fl];
        uint4 v2 = hb[(size_t)(int)l2 * 16 + fl];
        uint4 v3 = hb[(size_t)(int)l3 * 16 + fl];
        fma8(v0, __int_as_float((int)(l0 >> 32)));
        fma8(v1, __int_as_float((int)(l1 >> 32)));
        fma8(v2, __int_as_float((int)(l2 >> 32)));
        fma8(v3, __int_as_float((int)(l3 >> 32)));
    }
    for (int jj = n16 * 16; jj < cnt; jj += 4) {
        int idx = jj + qg;
        bool valid = idx < cnt;
        long long l = __builtin_nontemporal_load(ep + (valid ? idx : cnt - 1));
        float w = valid ? __int_as_float((int)(l >> 32)) : 0.f;
        uint4 v = hb[(size_t)(int)l * 16 + fl];
        fma8(v, w);
    }

    // combine the 4 quarter-groups
    a0 += __shfl_xor(a0, 16); a0 += __shfl_xor(a0, 32);
    a1 += __shfl_xor(a1, 16); a1 += __shfl_xor(a1, 32);
    a2 += __shfl_xor(a2, 16); a2 += __shfl_xor(a2, 32);
    a3 += __shfl_xor(a3, 16); a3 += __shfl_xor(a3, 32);
    a4 += __shfl_xor(a4, 16); a4 += __shfl_xor(a4, 32);
    a5 += __shfl_xor(a5, 16); a5 += __shfl_xor(a5, 32);
    a6 += __shfl_xor(a6, 16); a6 += __shfl_xor(a6, 32);
    a7 += __shfl_xor(a7, 16); a7 += __shfl_xor(a7, 32);

    if (qg == 0) {
        uint4 sv = hb[(size_t)node * 16 + fl];
        fma8(sv, 1.0f);                        // self-loop term: + hs[node]
        float di = dinv[node];
        float4 b0 = *(const float4*)(bias + fl * 8);
        float4 b1 = *(const float4*)(bias + fl * 8 + 4);
        a0 = fmaxf(di * a0 + b0.x, 0.f);
        a1 = fmaxf(di * a1 + b0.y, 0.f);
        a2 = fmaxf(di * a2 + b0.z, 0.f);
        a3 = fmaxf(di * a3 + b0.w, 0.f);
        a4 = fmaxf(di * a4 + b1.x, 0.f);
        a5 = fmaxf(di * a5 + b1.y, 0.f);
        a6 = fmaxf(di * a6 + b1.z, 0.f);
        a7 = fmaxf(di * a7 + b1.w, 0.f);
        u32x4 o;
        o.x = packbf(a0, a1); o.y = packbf(a2, a3);
        o.z = packbf(a4, a5); o.w = packbf(a6, a7);
        __builtin_nontemporal_store(o, (u32x4*)(outb + (size_t)node * 128 + fl * 8));
    }
}

// ---------------- segmented pooling (batch sorted): one block per graph --------------
__global__ __launch_bounds__(256) void k_pool(const unsigned short* __restrict__ h3,
                                              const int* __restrict__ batch,
                                              float* __restrict__ pooled) {
    __shared__ float sm[256];
    const int g = blockIdx.x;
    const int f = threadIdx.x & 127;
    const int half = threadIdx.x >> 7;
    // lower_bound(g), lower_bound(g+1)
    int lo = 0, hi = NN;
    while (lo < hi) { int m = (lo + hi) >> 1; if (batch[m] < g) lo = m + 1; else hi = m; }
    int s0 = lo;
    hi = NN;
    while (lo < hi) { int m = (lo + hi) >> 1; if (batch[m] < g + 1) lo = m + 1; else hi = m; }
    int e0 = lo;

    float s = 0.f;
    int n = s0 + half;
    for (; n + 8 <= e0; n += 8) {
        s += bfs(h3[(size_t)n * 128 + f]);
        s += bfs(h3[(size_t)(n + 2) * 128 + f]);
        s += bfs(h3[(size_t)(n + 4) * 128 + f]);
        s += bfs(h3[(size_t)(n + 6) * 128 + f]);
    }
    for (; n < e0; n += 2) s += bfs(h3[(size_t)n * 128 + f]);

    sm[threadIdx.x] = s;
    __syncthreads();
    if (half == 0) pooled[(size_t)g * 128 + f] = sm[threadIdx.x] + sm[threadIdx.x + 128];
}

// ---------------- FC + log_softmax: one wave per graph ----------------
__global__ __launch_bounds__(64) void k_fc(const float* __restrict__ pooled,
                                           const float* __restrict__ Wfc,
                                           const float* __restrict__ bfc,
                                           float* __restrict__ out) {
    const int g = blockIdx.x;
    const int lane = threadIdx.x;
    float p0 = pooled[(size_t)g * 128 + lane];
    float p1 = pooled[(size_t)g * 128 + 64 + lane];
    float logits[NC];
#pragma unroll
    for (int c = 0; c < NC; ++c) {
        float v = p0 * Wfc[lane * NC + c] + p1 * Wfc[(64 + lane) * NC + c];
#pragma unroll
        for (int off = 32; off > 0; off >>= 1) v += __shfl_down(v, off);
        logits[c] = v;
    }
    if (lane == 0) {
        float mx = -1e30f;
#pragma unroll
        for (int c = 0; c < NC; ++c) { logits[c] += bfc[c]; mx = fmaxf(mx, logits[c]); }
        float s = 0.f;
#pragma unroll
        for (int c = 0; c < NC; ++c) s += expf(logits[c] - mx);
        float lse = mx + logf(s);
#pragma unroll
        for (int c = 0; c < NC; ++c) out[(size_t)g * NC + c] = logits[c] - lse;
    }
}

extern "C" void kernel_launch(void* const* d_in, const int* in_sizes, int n_in,
                              void* d_out, int out_size, void* d_ws, size_t ws_size,
                              hipStream_t stream) {
    const float* x         = (const float*)d_in[0];
    const int*   edge_index= (const int*)d_in[1];
    const int*   batch     = (const int*)d_in[2];
    const float* edge_mask = (const float*)d_in[3];
    const float* W1        = (const float*)d_in[4];
    const float* b1        = (const float*)d_in[5];
    const float* W2        = (const float*)d_in[6];
    const float* b2        = (const float*)d_in[7];
    const float* Wfc       = (const float*)d_in[8];
    const float* bfc       = (const float*)d_in[9];
    float* out = (float*)d_out;

    const int* row = edge_index;        // edge_index[0]
    const int* col = edge_index + NE;   // edge_index[1]

    char* ws = (char*)d_ws;
    size_t off = 0;
    auto alloc = [&](size_t bytes) -> void* {
        off = (off + 255) & ~(size_t)255;
        void* p = ws + off;
        off += bytes;
        return p;
    };
    int*   counts   = (int*)  alloc((size_t)NN * 4);
    int*   offsets  = (int*)  alloc((size_t)NN * 4);
    int*   blockSums= (int*)  alloc(256 * 4);
    float* dinv     = (float*)alloc((size_t)NN * 4);
    int*   rank     = (int*)  alloc((size_t)NE * 4);
    long long* csr  = (long long*)alloc((size_t)NE * 8);
    unsigned short* xb  = (unsigned short*)alloc((size_t)NN * FEAT * 2); // x bf16
    unsigned short* hs1 = (unsigned short*)alloc((size_t)NN * FEAT * 2); // scaled bf16
    unsigned short* h2  = (unsigned short*)alloc((size_t)NN * FEAT * 2);
    unsigned short* h3  = (unsigned short*)alloc((size_t)NN * FEAT * 2);
    unsigned short* Wt1 = (unsigned short*)alloc((size_t)FEAT * FEAT * 2);
    unsigned short* Wt2 = (unsigned short*)alloc((size_t)FEAT * FEAT * 2);
    float* pooled   = (float*)alloc((size_t)NG * FEAT * 4);

    hipMemsetAsync(counts, 0, (size_t)NN * 4, stream);

    k_rank<<<(NE + 255) / 256, 256, 0, stream>>>(col, counts, rank);
    k_scanA<<<SCAN_BLOCKS, 256, 0, stream>>>(counts, offsets, blockSums);
    k_scanB<<<1, 256, 0, stream>>>(blockSums);
    k_scanC<<<SCAN_BLOCKS, 256, 0, stream>>>(offsets, blockSums);
    k_fill<<<(NE + 255) / 256, 256, 0, stream>>>(row, col, edge_mask, rank, offsets, csr);
    k_dinv2<<<(NN + 255) / 256, 256, 0, stream>>>(offsets, counts, csr, dinv);

    k_cast<<<(NN * FEAT / 8 + 255) / 256, 256, 0, stream>>>(x, xb);
    k_prepW<<<64, 256, 0, stream>>>(W1, Wt1);
    k_prepW<<<64, 256, 0, stream>>>(W2, Wt2);

    // layer 1: hs1 = dinv * (x @ W1); h2 = relu(b1 + dinv*(sum ew*hs1 + hs1))
    k_gemm_mfma<<<(NN + 63) / 64, 256, 0, stream>>>(xb, Wt1, dinv, hs1);
    k_agg<<<(NN + 3) / 4, 256, 0, stream>>>(hs1, offsets, counts, csr, dinv, b1, h2);
    // layer 2
    k_gemm_mfma<<<(NN + 63) / 64, 256, 0, stream>>>(h2, Wt2, dinv, hs1);
    k_agg<<<(NN + 3) / 4, 256, 0, stream>>>(hs1, offsets, counts, csr, dinv, b2, h3);
    // pool + FC
    k_pool<<<NG, 256, 0, stream>>>(h3, batch, pooled);
    k_fc<<<NG, 64, 0, stream>>>(pooled, Wfc, bfc, out);
}

// Round 9
// 396.250 us; speedup vs baseline: 1.7162x; 1.1084x over previous
//
#include <hip/hip_runtime.h>
#include <hip/hip_bf16.h>

#define NN 50000
#define NE 1600000
#define FEAT 128
#define NG 128
#define NC 10
#define CPAD 16  // counts padded: one counter per 64B line

constexpr int SCAN_BLOCKS = (NN + 255) / 256; // 196

typedef unsigned int u32x4 __attribute__((ext_vector_type(4)));
typedef short bf16x8 __attribute__((ext_vector_type(8)));
typedef float f32x4 __attribute__((ext_vector_type(4)));

// ---------------- bf16 helpers (manual, RNE) ----------------
__device__ __forceinline__ float bflo(unsigned u) { return __uint_as_float(u << 16); }
__device__ __forceinline__ float bfhi(unsigned u) { return __uint_as_float(u & 0xffff0000u); }
__device__ __forceinline__ float bfs(unsigned short u) { return __uint_as_float(((unsigned)u) << 16); }
__device__ __forceinline__ unsigned packbf(float a, float b) {
    unsigned ua = __float_as_uint(a), ub = __float_as_uint(b);
    ua += 0x7fffu + ((ua >> 16) & 1u);
    ub += 0x7fffu + ((ub >> 16) & 1u);
    return (ua >> 16) | (ub & 0xffff0000u);
}
__device__ __forceinline__ unsigned short bf1(float a) {
    unsigned ua = __float_as_uint(a);
    ua += 0x7fffu + ((ua >> 16) & 1u);
    return (unsigned short)(ua >> 16);
}

// ---------------- rank pass: padded-histogram + within-node rank ----------------
__global__ void k_rank(const int* __restrict__ col, int* __restrict__ counts,
                       int* __restrict__ rank) {
    int e = blockIdx.x * blockDim.x + threadIdx.x;
    if (e < NE) rank[e] = atomicAdd(&counts[(size_t)col[e] * CPAD], 1);
}

// ---------------- exclusive scan of padded counts -> offsets[NN+1] ----------------
__global__ void k_scanA(const int* __restrict__ counts, int* __restrict__ offsets,
                        int* __restrict__ blockSums) {
    __shared__ int tmp[256];
    int i = blockIdx.x * 256 + threadIdx.x;
    int v = (i < NN) ? counts[(size_t)i * CPAD] : 0;
    tmp[threadIdx.x] = v;
    __syncthreads();
    for (int off = 1; off < 256; off <<= 1) {
        int t = (threadIdx.x >= off) ? tmp[threadIdx.x - off] : 0;
        __syncthreads();
        tmp[threadIdx.x] += t;
        __syncthreads();
    }
    if (i < NN) offsets[i] = tmp[threadIdx.x] - v;
    if (threadIdx.x == 255) blockSums[blockIdx.x] = tmp[255];
}

__global__ void k_scanB(int* __restrict__ blockSums) {
    __shared__ int tmp[256];
    int t = threadIdx.x;
    int v = (t < SCAN_BLOCKS) ? blockSums[t] : 0;
    tmp[t] = v;
    __syncthreads();
    for (int off = 1; off < 256; off <<= 1) {
        int u = (t >= off) ? tmp[t - off] : 0;
        __syncthreads();
        tmp[t] += u;
        __syncthreads();
    }
    if (t < SCAN_BLOCKS) blockSums[t] = tmp[t] - v;
}

__global__ void k_scanC(int* __restrict__ offsets, const int* __restrict__ blockSums) {
    int i = blockIdx.x * 256 + threadIdx.x;
    if (i < NN) offsets[i] += blockSums[blockIdx.x];
    if (i == 0) offsets[NN] = NE; // sentinel
}

// ---------------- CSR fill: NO atomics, plain (cacheable) stores ----------------
__global__ void k_fill(const int* __restrict__ row, const int* __restrict__ col,
                       const float* __restrict__ ew, const int* __restrict__ rank,
                       const int* __restrict__ offsets, long long* __restrict__ csr) {
    int e = blockIdx.x * blockDim.x + threadIdx.x;
    if (e < NE) {
        int pos = offsets[col[e]] + rank[e];
        long long v = (long long)(unsigned)row[e] | ((long long)__float_as_int(ew[e]) << 32);
        csr[pos] = v;
    }
}

// ---------------- dinv from CSR segments (no atomics) ----------------
__global__ void k_dinv2(const int* __restrict__ offsets, const long long* __restrict__ csr,
                        float* __restrict__ dinv) {
    int n = blockIdx.x * blockDim.x + threadIdx.x;
    if (n >= NN) return;
    int s = offsets[n], e = offsets[n + 1];
    float d = 0.f;
    for (int j = s; j < e; ++j)
        d += __int_as_float((int)(csr[j] >> 32));
    dinv[n] = rsqrtf(d + 1.0f); // +1 = self-loop weight
}

// ---------------- W[k][n] f32 -> Wt[n][k] bf16 ----------------
__global__ void k_prepW(const float* __restrict__ W, unsigned short* __restrict__ Wt) {
    int idx = blockIdx.x * 256 + threadIdx.x; // 16384 threads
    int k = idx >> 7, n = idx & 127;
    Wt[n * 128 + k] = bf1(W[idx]);
}

// ---------------- MFMA GEMM: C_bf16 = dinv[row] * (A[NN x 128] @ W[128 x 128]) ----
// A row-major (f32 or bf16), Wt = W^T row-major bf16 [n][k]. No LDS.
// Per wave: 16 rows x 128 cols. mfma_f32_16x16x32_bf16:
//   A frag: row = lane&15, k = (lane>>4)*8 + j   (k-perm consistent A/B cancels)
//   D: col = lane&15, row = (lane>>4)*4 + reg    (m89-verified)
template <typename TIN>
__global__ __launch_bounds__(256) void k_gemm_mfma(const TIN* __restrict__ A,
                                                   const unsigned short* __restrict__ Wt,
                                                   const float* __restrict__ dinv,
                                                   unsigned short* __restrict__ C) {
    const int t = threadIdx.x;
    const int wid = t >> 6;
    const int lane = t & 63;
    const int row0 = blockIdx.x * 64 + wid * 16;
    const int l15 = lane & 15;
    const int kg = lane >> 4; // 0..3

    int arow = row0 + l15;
    if (arow >= NN) arow = NN - 1; // clamp; stores guarded
    bf16x8 a[4];
    if constexpr (sizeof(TIN) == 2) {
        const unsigned short* ap = (const unsigned short*)A + (size_t)arow * 128 + kg * 8;
#pragma unroll
        for (int ks = 0; ks < 4; ++ks)
            a[ks] = *(const bf16x8*)(ap + ks * 32);
    } else {
        const float* ap = (const float*)A + (size_t)arow * 128 + kg * 8;
#pragma unroll
        for (int ks = 0; ks < 4; ++ks) {
            float4 v0 = *(const float4*)(ap + ks * 32);
            float4 v1 = *(const float4*)(ap + ks * 32 + 4);
            u32x4 o;
            o.x = packbf(v0.x, v0.y); o.y = packbf(v0.z, v0.w);
            o.z = packbf(v1.x, v1.y); o.w = packbf(v1.z, v1.w);
            a[ks] = __builtin_bit_cast(bf16x8, o);
        }
    }

    f32x4 acc[8];
#pragma unroll
    for (int ct = 0; ct < 8; ++ct) acc[ct] = (f32x4){0.f, 0.f, 0.f, 0.f};

#pragma unroll
    for (int ct = 0; ct < 8; ++ct) {
        const unsigned short* bp = Wt + (size_t)(ct * 16 + l15) * 128 + kg * 8;
#pragma unroll
        for (int ks = 0; ks < 4; ++ks) {
            bf16x8 b = *(const bf16x8*)(bp + ks * 32);
            acc[ct] = __builtin_amdgcn_mfma_f32_16x16x32_bf16(a[ks], b, acc[ct], 0, 0, 0);
        }
    }

    const int drow0 = row0 + kg * 4;
    float di[4];
#pragma unroll
    for (int r = 0; r < 4; ++r)
        di[r] = (drow0 + r < NN) ? dinv[drow0 + r] : 0.f;
#pragma unroll
    for (int ct = 0; ct < 8; ++ct) {
#pragma unroll
        for (int r = 0; r < 4; ++r) {
            int grow = drow0 + r;
            if (grow < NN)
                C[(size_t)grow * 128 + ct * 16 + l15] = bf1(acc[ct][r] * di[r]);
        }
    }
}

// ---------------- pull aggregation: quarter-wave (16 lanes = one 256B row) ----------
// out[n] = relu( b + dinv[n] * ( sum_e ew_e * hs[row_e] + hs[n] ) ), bf16 out
__global__ __launch_bounds__(256) void k_agg(const unsigned short* __restrict__ hs,
                                             const int* __restrict__ offsets,
                                             const long long* __restrict__ csr,
                                             const float* __restrict__ dinv,
                                             const float* __restrict__ bias,
                                             unsigned short* __restrict__ outb) {
    const int node = blockIdx.x * 4 + (threadIdx.x >> 6);
    if (node >= NN) return;
    const int lane = threadIdx.x & 63;
    const int qg = lane >> 4;   // quarter-group: which edge of 4
    const int fl = lane & 15;   // feature lane: owns feats [fl*8, fl*8+8)

    const int start = offsets[node];
    const int cnt = offsets[node + 1] - start;
    const long long* ep = csr + start;
    const uint4* hb = (const uint4*)hs;

    float a0 = 0.f, a1 = 0.f, a2 = 0.f, a3 = 0.f;
    float a4 = 0.f, a5 = 0.f, a6 = 0.f, a7 = 0.f;

    auto fma8 = [&](uint4 v, float w) {
        a0 += bflo(v.x) * w; a1 += bfhi(v.x) * w;
        a2 += bflo(v.y) * w; a3 += bfhi(v.y) * w;
        a4 += bflo(v.z) * w; a5 += bfhi(v.z) * w;
        a6 += bflo(v.w) * w; a7 += bfhi(v.w) * w;
    };

    const int n16 = cnt >> 4;
    for (int i = 0; i < n16; ++i) {
        const int base = i * 16 + qg;
        long long l0 = __builtin_nontemporal_load(ep + base);
        long long l1 = __builtin_nontemporal_load(ep + base + 4);
        long long l2 = __builtin_nontemporal_load(ep + base + 8);
        long long l3 = __builtin_nontemporal_load(ep + base + 12);
        uint4 v0 = hb[(size_t)(int)l0 * 16 + fl];
        uint4 v1 = hb[(size_t)(int)l1 * 16 + fl];
        uint4 v2 = hb[(size_t)(int)l2 * 16 + fl];
        uint4 v3 = hb[(size_t)(int)l3 * 16 + fl];
        fma8(v0, __int_as_float((int)(l0 >> 32)));
        fma8(v1, __int_as_float((int)(l1 >> 32)));
        fma8(v2, __int_as_float((int)(l2 >> 32)));
        fma8(v3, __int_as_float((int)(l3 >> 32)));
    }
    for (int jj = n16 * 16; jj < cnt; jj += 4) {
        int idx = jj + qg;
        bool valid = idx < cnt;
        long long l = __builtin_nontemporal_load(ep + (valid ? idx : cnt - 1));
        float w = valid ? __int_as_float((int)(l >> 32)) : 0.f;
        uint4 v = hb[(size_t)(int)l * 16 + fl];
        fma8(v, w);
    }

    // combine the 4 quarter-groups
    a0 += __shfl_xor(a0, 16); a0 += __shfl_xor(a0, 32);
    a1 += __shfl_xor(a1, 16); a1 += __shfl_xor(a1, 32);
    a2 += __shfl_xor(a2, 16); a2 += __shfl_xor(a2, 32);
    a3 += __shfl_xor(a3, 16); a3 += __shfl_xor(a3, 32);
    a4 += __shfl_xor(a4, 16); a4 += __shfl_xor(a4, 32);
    a5 += __shfl_xor(a5, 16); a5 += __shfl_xor(a5, 32);
    a6 += __shfl_xor(a6, 16); a6 += __shfl_xor(a6, 32);
    a7 += __shfl_xor(a7, 16); a7 += __shfl_xor(a7, 32);

    if (qg == 0) {
        uint4 sv = hb[(size_t)node * 16 + fl];
        fma8(sv, 1.0f);                        // self-loop term: + hs[node]
        float di = dinv[node];
        float4 b0 = *(const float4*)(bias + fl * 8);
        float4 b1 = *(const float4*)(bias + fl * 8 + 4);
        a0 = fmaxf(di * a0 + b0.x, 0.f);
        a1 = fmaxf(di * a1 + b0.y, 0.f);
        a2 = fmaxf(di * a2 + b0.z, 0.f);
        a3 = fmaxf(di * a3 + b0.w, 0.f);
        a4 = fmaxf(di * a4 + b1.x, 0.f);
        a5 = fmaxf(di * a5 + b1.y, 0.f);
        a6 = fmaxf(di * a6 + b1.z, 0.f);
        a7 = fmaxf(di * a7 + b1.w, 0.f);
        u32x4 o;
        o.x = packbf(a0, a1); o.y = packbf(a2, a3);
        o.z = packbf(a4, a5); o.w = packbf(a6, a7);
        __builtin_nontemporal_store(o, (u32x4*)(outb + (size_t)node * 128 + fl * 8));
    }
}

// ---------------- segmented pooling (batch sorted): one block per graph --------------
__global__ __launch_bounds__(256) void k_pool(const unsigned short* __restrict__ h3,
                                              const int* __restrict__ batch,
                                              float* __restrict__ pooled) {
    __shared__ float sm[256];
    const int g = blockIdx.x;
    const int f = threadIdx.x & 127;
    const int half = threadIdx.x >> 7;
    // lower_bound(g), lower_bound(g+1)
    int lo = 0, hi = NN;
    while (lo < hi) { int m = (lo + hi) >> 1; if (batch[m] < g) lo = m + 1; else hi = m; }
    int s0 = lo;
    hi = NN;
    while (lo < hi) { int m = (lo + hi) >> 1; if (batch[m] < g + 1) lo = m + 1; else hi = m; }
    int e0 = lo;

    float s = 0.f;
    int n = s0 + half;
    for (; n + 8 <= e0; n += 8) {
        s += bfs(h3[(size_t)n * 128 + f]);
        s += bfs(h3[(size_t)(n + 2) * 128 + f]);
        s += bfs(h3[(size_t)(n + 4) * 128 + f]);
        s += bfs(h3[(size_t)(n + 6) * 128 + f]);
    }
    for (; n < e0; n += 2) s += bfs(h3[(size_t)n * 128 + f]);

    sm[threadIdx.x] = s;
    __syncthreads();
    if (half == 0) pooled[(size_t)g * 128 + f] = sm[threadIdx.x] + sm[threadIdx.x + 128];
}

// ---------------- FC + log_softmax: one wave per graph ----------------
__global__ __launch_bounds__(64) void k_fc(const float* __restrict__ pooled,
                                           const float* __restrict__ Wfc,
                                           const float* __restrict__ bfc,
                                           float* __restrict__ out) {
    const int g = blockIdx.x;
    const int lane = threadIdx.x;
    float p0 = pooled[(size_t)g * 128 + lane];
    float p1 = pooled[(size_t)g * 128 + 64 + lane];
    float logits[NC];
#pragma unroll
    for (int c = 0; c < NC; ++c) {
        float v = p0 * Wfc[lane * NC + c] + p1 * Wfc[(64 + lane) * NC + c];
#pragma unroll
        for (int off = 32; off > 0; off >>= 1) v += __shfl_down(v, off);
        logits[c] = v;
    }
    if (lane == 0) {
        float mx = -1e30f;
#pragma unroll
        for (int c = 0; c < NC; ++c) { logits[c] += bfc[c]; mx = fmaxf(mx, logits[c]); }
        float s = 0.f;
#pragma unroll
        for (int c = 0; c < NC; ++c) s += expf(logits[c] - mx);
        float lse = mx + logf(s);
#pragma unroll
        for (int c = 0; c < NC; ++c) out[(size_t)g * NC + c] = logits[c] - lse;
    }
}

extern "C" void kernel_launch(void* const* d_in, const int* in_sizes, int n_in,
                              void* d_out, int out_size, void* d_ws, size_t ws_size,
                              hipStream_t stream) {
    const float* x         = (const float*)d_in[0];
    const int*   edge_index= (const int*)d_in[1];
    const int*   batch     = (const int*)d_in[2];
    const float* edge_mask = (const float*)d_in[3];
    const float* W1        = (const float*)d_in[4];
    const float* b1        = (const float*)d_in[5];
    const float* W2        = (const float*)d_in[6];
    const float* b2        = (const float*)d_in[7];
    const float* Wfc       = (const float*)d_in[8];
    const float* bfc       = (const float*)d_in[9];
    float* out = (float*)d_out;

    const int* row = edge_index;        // edge_index[0]
    const int* col = edge_index + NE;   // edge_index[1]

    char* ws = (char*)d_ws;
    size_t off = 0;
    auto alloc = [&](size_t bytes) -> void* {
        off = (off + 255) & ~(size_t)255;
        void* p = ws + off;
        off += bytes;
        return p;
    };
    int*   counts   = (int*)  alloc((size_t)NN * CPAD * 4); // padded: 1 counter / 64B
    int*   offsets  = (int*)  alloc((size_t)(NN + 1) * 4);
    int*   blockSums= (int*)  alloc(256 * 4);
    float* dinv     = (float*)alloc((size_t)NN * 4);
    int*   rank     = (int*)  alloc((size_t)NE * 4);
    long long* csr  = (long long*)alloc((size_t)NE * 8);
    unsigned short* hs1 = (unsigned short*)alloc((size_t)NN * FEAT * 2); // scaled bf16
    unsigned short* h2  = (unsigned short*)alloc((size_t)NN * FEAT * 2);
    unsigned short* h3  = (unsigned short*)alloc((size_t)NN * FEAT * 2);
    unsigned short* Wt1 = (unsigned short*)alloc((size_t)FEAT * FEAT * 2);
    unsigned short* Wt2 = (unsigned short*)alloc((size_t)FEAT * FEAT * 2);
    float* pooled   = (float*)alloc((size_t)NG * FEAT * 4);

    hipMemsetAsync(counts, 0, (size_t)NN * CPAD * 4, stream);

    k_rank<<<(NE + 255) / 256, 256, 0, stream>>>(col, counts, rank);
    k_scanA<<<SCAN_BLOCKS, 256, 0, stream>>>(counts, offsets, blockSums);
    k_scanB<<<1, 256, 0, stream>>>(blockSums);
    k_scanC<<<SCAN_BLOCKS, 256, 0, stream>>>(offsets, blockSums);
    k_fill<<<(NE + 255) / 256, 256, 0, stream>>>(row, col, edge_mask, rank, offsets, csr);
    k_dinv2<<<(NN + 255) / 256, 256, 0, stream>>>(offsets, csr, dinv);

    k_prepW<<<64, 256, 0, stream>>>(W1, Wt1);
    k_prepW<<<64, 256, 0, stream>>>(W2, Wt2);

    // layer 1: hs1 = dinv * (x @ W1); h2 = relu(b1 + dinv*(sum ew*hs1 + hs1))
    k_gemm_mfma<float><<<(NN + 63) / 64, 256, 0, stream>>>(x, Wt1, dinv, hs1);
    k_agg<<<(NN + 3) / 4, 256, 0, stream>>>(hs1, offsets, csr, dinv, b1, h2);
    // layer 2
    k_gemm_mfma<unsigned short><<<(NN + 63) / 64, 256, 0, stream>>>(h2, Wt2, dinv, hs1);
    k_agg<<<(NN + 3) / 4, 256, 0, stream>>>(hs1, offsets, csr, dinv, b2, h3);
    // pool + FC
    k_pool<<<NG, 256, 0, stream>>>(h3, batch, pooled);
    k_fc<<<NG, 64, 0, stream>>>(pooled, Wfc, bfc, out);
}

// Round 11
// 371.893 us; speedup vs baseline: 1.8286x; 1.0655x over previous
//
#include <hip/hip_runtime.h>
#include <hip/hip_bf16.h>

#define NN 50000
#define NE 1600000
#define FEAT 128
#define NG 128
#define NC 10

#define BUCK 256
#define NBUCK ((NN + BUCK - 1) / BUCK)   // 196
#define EPB 8192
#define NBLK1 ((NE + EPB - 1) / EPB)     // 196

typedef unsigned int u32x4 __attribute__((ext_vector_type(4)));
typedef short bf16x8 __attribute__((ext_vector_type(8)));
typedef float f32x4 __attribute__((ext_vector_type(4)));

// ---------------- bf16 helpers (manual, RNE) ----------------
__device__ __forceinline__ float bflo(unsigned u) { return __uint_as_float(u << 16); }
__device__ __forceinline__ float bfhi(unsigned u) { return __uint_as_float(u & 0xffff0000u); }
__device__ __forceinline__ float bfs(unsigned short u) { return __uint_as_float(((unsigned)u) << 16); }
__device__ __forceinline__ unsigned packbf(float a, float b) {
    unsigned ua = __float_as_uint(a), ub = __float_as_uint(b);
    ua += 0x7fffu + ((ua >> 16) & 1u);
    ub += 0x7fffu + ((ub >> 16) & 1u);
    return (ua >> 16) | (ub & 0xffff0000u);
}
__device__ __forceinline__ unsigned short bf1(float a) {
    unsigned ua = __float_as_uint(a);
    ua += 0x7fffu + ((ua >> 16) & 1u);
    return (unsigned short)(ua >> 16);
}

// ---------------- p1a: per-block bucket histogram (LDS atomics only) ----------------
__global__ __launch_bounds__(256) void k_hist(const int* __restrict__ col,
                                              int* __restrict__ blockHist) {
    __shared__ int h[BUCK];
    h[threadIdx.x] = 0;
    __syncthreads();
    const int base = blockIdx.x * EPB;
    const int end = min(base + EPB, NE);
    for (int e = base + threadIdx.x; e < end; e += 256)
        atomicAdd(&h[col[e] >> 8], 1);
    __syncthreads();
    blockHist[threadIdx.x * NBLK1 + blockIdx.x] = h[threadIdx.x];
}

// ---------------- p1b: per-bucket block-prefix + bucket-total scan ----------------
__global__ __launch_bounds__(256) void k_scanbk(int* __restrict__ blockHist,
                                                int* __restrict__ bucketOff,
                                                int* __restrict__ offsets) {
    __shared__ int tmp[256];
    const int t = threadIdx.x;
    int sum = 0;
    if (t < NBUCK) {
        for (int blk = 0; blk < NBLK1; ++blk) {
            int v = blockHist[t * NBLK1 + blk];
            blockHist[t * NBLK1 + blk] = sum; // within-bucket exclusive prefix
            sum += v;
        }
    }
    tmp[t] = sum;
    __syncthreads();
    for (int d = 1; d < 256; d <<= 1) {
        int u = (t >= d) ? tmp[t - d] : 0;
        __syncthreads();
        tmp[t] += u;
        __syncthreads();
    }
    const int excl = tmp[t] - sum;
    if (t < NBUCK) {
        bucketOff[t] = excl;
        for (int blk = 0; blk < NBLK1; ++blk)
            blockHist[t * NBLK1 + blk] += excl;
    }
    if (t == 0) { bucketOff[NBUCK] = NE; offsets[NN] = NE; }
}

// ---------------- p1c: scatter packed records into bucket-grouped order ----------------
// record: lo32 = row(16b) | c_local(8b)<<16 ; hi32 = ew bits
__global__ __launch_bounds__(256) void k_scatter(const int* __restrict__ row,
                                                 const int* __restrict__ col,
                                                 const float* __restrict__ ew,
                                                 const int* __restrict__ blockHist,
                                                 long long* __restrict__ binned) {
    __shared__ int cur[BUCK];
    cur[threadIdx.x] = blockHist[threadIdx.x * NBLK1 + blockIdx.x];
    __syncthreads();
    const int base = blockIdx.x * EPB;
    const int end = min(base + EPB, NE);
    for (int e = base + threadIdx.x; e < end; e += 256) {
        int c = col[e];
        int pos = atomicAdd(&cur[c >> 8], 1);
        long long v = (long long)(unsigned)(row[e] | ((c & 255) << 16)) |
                      ((long long)__float_as_int(ew[e]) << 32);
        binned[pos] = v;
    }
}

// ---------------- p2: per-bucket CSR finalize + offsets + dinv (LDS atomics) ----------
__global__ __launch_bounds__(256) void k_csr(const long long* __restrict__ binned,
                                             const int* __restrict__ bucketOff,
                                             long long* __restrict__ csr,
                                             int* __restrict__ offsets,
                                             float* __restrict__ dinv) {
    __shared__ int cnt[BUCK], off[BUCK], cnt2[BUCK];
    __shared__ float wsum[BUCK];
    const int b = blockIdx.x;
    const int t = threadIdx.x;
    cnt[t] = 0; cnt2[t] = 0; wsum[t] = 0.f;
    __syncthreads();
    const int s = bucketOff[b], e = bucketOff[b + 1];
    for (int i = s + t; i < e; i += 256) {
        int lo = (int)binned[i];
        atomicAdd(&cnt[(lo >> 16) & 255], 1);
    }
    __syncthreads();
    // exclusive scan cnt -> off
    int v0 = cnt[t];
    off[t] = v0;
    __syncthreads();
    for (int d = 1; d < 256; d <<= 1) {
        int u = (t >= d) ? off[t - d] : 0;
        __syncthreads();
        off[t] += u;
        __syncthreads();
    }
    int myoff = off[t] - v0;
    __syncthreads();
    off[t] = myoff;
    __syncthreads();
    for (int i = s + t; i < e; i += 256) {
        long long v = binned[i];
        int lo = (int)v;
        int c = (lo >> 16) & 255;
        int r = atomicAdd(&cnt2[c], 1);
        atomicAdd(&wsum[c], __int_as_float((int)(v >> 32)));
        csr[s + off[c] + r] = (long long)(unsigned)(lo & 0xFFFF) |
                              (v & 0xFFFFFFFF00000000LL);
    }
    __syncthreads();
    const int node = b * BUCK + t;
    if (node < NN) {
        offsets[node] = s + off[t];
        dinv[node] = rsqrtf(wsum[t] + 1.0f); // +1 = self-loop weight
    }
}

// ---------------- W[k][n] f32 -> Wt[n][k] bf16 ----------------
__global__ void k_prepW(const float* __restrict__ W, unsigned short* __restrict__ Wt) {
    int idx = blockIdx.x * 256 + threadIdx.x; // 16384 threads
    int k = idx >> 7, n = idx & 127;
    Wt[n * 128 + k] = bf1(W[idx]);
}

// ---------------- MFMA GEMM: C_bf16 = dinv[row] * (A[NN x 128] @ W[128 x 128]) ----
template <typename TIN>
__global__ __launch_bounds__(256) void k_gemm_mfma(const TIN* __restrict__ A,
                                                   const unsigned short* __restrict__ Wt,
                                                   const float* __restrict__ dinv,
                                                   unsigned short* __restrict__ C) {
    const int t = threadIdx.x;
    const int wid = t >> 6;
    const int lane = t & 63;
    const int row0 = blockIdx.x * 64 + wid * 16;
    const int l15 = lane & 15;
    const int kg = lane >> 4; // 0..3

    int arow = row0 + l15;
    if (arow >= NN) arow = NN - 1; // clamp; stores guarded
    bf16x8 a[4];
    if constexpr (sizeof(TIN) == 2) {
        const unsigned short* ap = (const unsigned short*)A + (size_t)arow * 128 + kg * 8;
#pragma unroll
        for (int ks = 0; ks < 4; ++ks)
            a[ks] = *(const bf16x8*)(ap + ks * 32);
    } else {
        const float* ap = (const float*)A + (size_t)arow * 128 + kg * 8;
#pragma unroll
        for (int ks = 0; ks < 4; ++ks) {
            float4 v0 = *(const float4*)(ap + ks * 32);
            float4 v1 = *(const float4*)(ap + ks * 32 + 4);
            u32x4 o;
            o.x = packbf(v0.x, v0.y); o.y = packbf(v0.z, v0.w);
            o.z = packbf(v1.x, v1.y); o.w = packbf(v1.z, v1.w);
            a[ks] = __builtin_bit_cast(bf16x8, o);
        }
    }

    f32x4 acc[8];
#pragma unroll
    for (int ct = 0; ct < 8; ++ct) acc[ct] = (f32x4){0.f, 0.f, 0.f, 0.f};

#pragma unroll
    for (int ct = 0; ct < 8; ++ct) {
        const unsigned short* bp = Wt + (size_t)(ct * 16 + l15) * 128 + kg * 8;
#pragma unroll
        for (int ks = 0; ks < 4; ++ks) {
            bf16x8 b = *(const bf16x8*)(bp + ks * 32);
            acc[ct] = __builtin_amdgcn_mfma_f32_16x16x32_bf16(a[ks], b, acc[ct], 0, 0, 0);
        }
    }

    const int drow0 = row0 + kg * 4;
    float di[4];
#pragma unroll
    for (int r = 0; r < 4; ++r)
        di[r] = (drow0 + r < NN) ? dinv[drow0 + r] : 0.f;
#pragma unroll
    for (int ct = 0; ct < 8; ++ct) {
#pragma unroll
        for (int r = 0; r < 4; ++r) {
            int grow = drow0 + r;
            if (grow < NN)
                C[(size_t)grow * 128 + ct * 16 + l15] = bf1(acc[ct][r] * di[r]);
        }
    }
}

// ---------------- pull aggregation: quarter-wave (16 lanes = one 256B row) ----------
__global__ __launch_bounds__(256) void k_agg(const unsigned short* __restrict__ hs,
                                             const int* __restrict__ offsets,
                                             const long long* __restrict__ csr,
                                             const float* __restrict__ dinv,
                                             const float* __restrict__ bias,
                                             unsigned short* __restrict__ outb) {
    const int node = blockIdx.x * 4 + (threadIdx.x >> 6);
    if (node >= NN) return;
    const int lane = threadIdx.x & 63;
    const int qg = lane >> 4;   // quarter-group: which edge of 4
    const int fl = lane & 15;   // feature lane: owns feats [fl*8, fl*8+8)

    const int start = offsets[node];
    const int cnt = offsets[node + 1] - start;
    const long long* ep = csr + start;
    const uint4* hb = (const uint4*)hs;

    float a0 = 0.f, a1 = 0.f, a2 = 0.f, a3 = 0.f;
    float a4 = 0.f, a5 = 0.f, a6 = 0.f, a7 = 0.f;

    auto fma8 = [&](uint4 v, float w) {
        a0 += bflo(v.x) * w; a1 += bfhi(v.x) * w;
        a2 += bflo(v.y) * w; a3 += bfhi(v.y) * w;
        a4 += bflo(v.z) * w; a5 += bfhi(v.z) * w;
        a6 += bflo(v.w) * w; a7 += bfhi(v.w) * w;
    };

    const int n16 = cnt >> 4;
    for (int i = 0; i < n16; ++i) {
        const int base = i * 16 + qg;
        long long l0 = __builtin_nontemporal_load(ep + base);
        long long l1 = __builtin_nontemporal_load(ep + base + 4);
        long long l2 = __builtin_nontemporal_load(ep + base + 8);
        long long l3 = __builtin_nontemporal_load(ep + base + 12);
        uint4 v0 = hb[(size_t)(int)l0 * 16 + fl];
        uint4 v1 = hb[(size_t)(int)l1 * 16 + fl];
        uint4 v2 = hb[(size_t)(int)l2 * 16 + fl];
        uint4 v3 = hb[(size_t)(int)l3 * 16 + fl];
        fma8(v0, __int_as_float((int)(l0 >> 32)));
        fma8(v1, __int_as_float((int)(l1 >> 32)));
        fma8(v2, __int_as_float((int)(l2 >> 32)));
        fma8(v3, __int_as_float((int)(l3 >> 32)));
    }
    for (int jj = n16 * 16; jj < cnt; jj += 4) {
        int idx = jj + qg;
        bool valid = idx < cnt;
        long long l = __builtin_nontemporal_load(ep + (valid ? idx : cnt - 1));
        float w = valid ? __int_as_float((int)(l >> 32)) : 0.f;
        uint4 v = hb[(size_t)(int)l * 16 + fl];
        fma8(v, w);
    }

    a0 += __shfl_xor(a0, 16); a0 += __shfl_xor(a0, 32);
    a1 += __shfl_xor(a1, 16); a1 += __shfl_xor(a1, 32);
    a2 += __shfl_xor(a2, 16); a2 += __shfl_xor(a2, 32);
    a3 += __shfl_xor(a3, 16); a3 += __shfl_xor(a3, 32);
    a4 += __shfl_xor(a4, 16); a4 += __shfl_xor(a4, 32);
    a5 += __shfl_xor(a5, 16); a5 += __shfl_xor(a5, 32);
    a6 += __shfl_xor(a6, 16); a6 += __shfl_xor(a6, 32);
    a7 += __shfl_xor(a7, 16); a7 += __shfl_xor(a7, 32);

    if (qg == 0) {
        uint4 sv = hb[(size_t)node * 16 + fl];
        fma8(sv, 1.0f);                        // self-loop term: + hs[node]
        float di = dinv[node];
        float4 b0 = *(const float4*)(bias + fl * 8);
        float4 b1 = *(const float4*)(bias + fl * 8 + 4);
        a0 = fmaxf(di * a0 + b0.x, 0.f);
        a1 = fmaxf(di * a1 + b0.y, 0.f);
        a2 = fmaxf(di * a2 + b0.z, 0.f);
        a3 = fmaxf(di * a3 + b0.w, 0.f);
        a4 = fmaxf(di * a4 + b1.x, 0.f);
        a5 = fmaxf(di * a5 + b1.y, 0.f);
        a6 = fmaxf(di * a6 + b1.z, 0.f);
        a7 = fmaxf(di * a7 + b1.w, 0.f);
        u32x4 o;
        o.x = packbf(a0, a1); o.y = packbf(a2, a3);
        o.z = packbf(a4, a5); o.w = packbf(a6, a7);
        __builtin_nontemporal_store(o, (u32x4*)(outb + (size_t)node * 128 + fl * 8));
    }
}

// ---------------- segmented pooling (batch sorted): one block per graph --------------
__global__ __launch_bounds__(256) void k_pool(const unsigned short* __restrict__ h3,
                                              const int* __restrict__ batch,
                                              float* __restrict__ pooled) {
    __shared__ float sm[256];
    const int g = blockIdx.x;
    const int f = threadIdx.x & 127;
    const int half = threadIdx.x >> 7;
    int lo = 0, hi = NN;
    while (lo < hi) { int m = (lo + hi) >> 1; if (batch[m] < g) lo = m + 1; else hi = m; }
    int s0 = lo;
    hi = NN;
    while (lo < hi) { int m = (lo + hi) >> 1; if (batch[m] < g + 1) lo = m + 1; else hi = m; }
    int e0 = lo;

    float s = 0.f;
    int n = s0 + half;
    for (; n + 8 <= e0; n += 8) {
        s += bfs(h3[(size_t)n * 128 + f]);
        s += bfs(h3[(size_t)(n + 2) * 128 + f]);
        s += bfs(h3[(size_t)(n + 4) * 128 + f]);
        s += bfs(h3[(size_t)(n + 6) * 128 + f]);
    }
    for (; n < e0; n += 2) s += bfs(h3[(size_t)n * 128 + f]);

    sm[threadIdx.x] = s;
    __syncthreads();
    if (half == 0) pooled[(size_t)g * 128 + f] = sm[threadIdx.x] + sm[threadIdx.x + 128];
}

// ---------------- FC + log_softmax: one wave per graph ----------------
__global__ __launch_bounds__(64) void k_fc(const float* __restrict__ pooled,
                                           const float* __restrict__ Wfc,
                                           const float* __restrict__ bfc,
                                           float* __restrict__ out) {
    const int g = blockIdx.x;
    const int lane = threadIdx.x;
    float p0 = pooled[(size_t)g * 128 + lane];
    float p1 = pooled[(size_t)g * 128 + 64 + lane];
    float logits[NC];
#pragma unroll
    for (int c = 0; c < NC; ++c) {
        float v = p0 * Wfc[lane * NC + c] + p1 * Wfc[(64 + lane) * NC + c];
#pragma unroll
        for (int off = 32; off > 0; off >>= 1) v += __shfl_down(v, off);
        logits[c] = v;
    }
    if (lane == 0) {
        float mx = -1e30f;
#pragma unroll
        for (int c = 0; c < NC; ++c) { logits[c] += bfc[c]; mx = fmaxf(mx, logits[c]); }
        float s = 0.f;
#pragma unroll
        for (int c = 0; c < NC; ++c) s += expf(logits[c] - mx);
        float lse = mx + logf(s);
#pragma unroll
        for (int c = 0; c < NC; ++c) out[(size_t)g * NC + c] = logits[c] - lse;
    }
}

extern "C" void kernel_launch(void* const* d_in, const int* in_sizes, int n_in,
                              void* d_out, int out_size, void* d_ws, size_t ws_size,
                              hipStream_t stream) {
    const float* x         = (const float*)d_in[0];
    const int*   edge_index= (const int*)d_in[1];
    const int*   batch     = (const int*)d_in[2];
    const float* edge_mask = (const float*)d_in[3];
    const float* W1        = (const float*)d_in[4];
    const float* b1        = (const float*)d_in[5];
    const float* W2        = (const float*)d_in[6];
    const float* b2        = (const float*)d_in[7];
    const float* Wfc       = (const float*)d_in[8];
    const float* bfc       = (const float*)d_in[9];
    float* out = (float*)d_out;

    const int* row = edge_index;        // edge_index[0]
    const int* col = edge_index + NE;   // edge_index[1]

    char* ws = (char*)d_ws;
    size_t off = 0;
    auto alloc = [&](size_t bytes) -> void* {
        off = (off + 255) & ~(size_t)255;
        void* p = ws + off;
        off += bytes;
        return p;
    };
    int*   blockHist= (int*)  alloc((size_t)256 * NBLK1 * 4);
    int*   bucketOff= (int*)  alloc((size_t)(NBUCK + 1) * 4);
    int*   offsets  = (int*)  alloc((size_t)(NN + 1) * 4);
    float* dinv     = (float*)alloc((size_t)NN * 4);
    long long* binned = (long long*)alloc((size_t)NE * 8);
    long long* csr  = (long long*)alloc((size_t)NE * 8);
    unsigned short* hs1 = (unsigned short*)alloc((size_t)NN * FEAT * 2); // scaled bf16
    unsigned short* h2  = (unsigned short*)alloc((size_t)NN * FEAT * 2);
    unsigned short* h3  = (unsigned short*)alloc((size_t)NN * FEAT * 2);
    unsigned short* Wt1 = (unsigned short*)alloc((size_t)FEAT * FEAT * 2);
    unsigned short* Wt2 = (unsigned short*)alloc((size_t)FEAT * FEAT * 2);
    float* pooled   = (float*)alloc((size_t)NG * FEAT * 4);

    // ---- CSR build: zero global atomics ----
    k_hist<<<NBLK1, 256, 0, stream>>>(col, blockHist);
    k_scanbk<<<1, 256, 0, stream>>>(blockHist, bucketOff, offsets);
    k_scatter<<<NBLK1, 256, 0, stream>>>(row, col, edge_mask, blockHist, binned);
    k_csr<<<NBUCK, 256, 0, stream>>>(binned, bucketOff, csr, offsets, dinv);

    k_prepW<<<64, 256, 0, stream>>>(W1, Wt1);
    k_prepW<<<64, 256, 0, stream>>>(W2, Wt2);

    // layer 1: hs1 = dinv * (x @ W1); h2 = relu(b1 + dinv*(sum ew*hs1 + hs1))
    k_gemm_mfma<float><<<(NN + 63) / 64, 256, 0, stream>>>(x, Wt1, dinv, hs1);
    k_agg<<<(NN + 3) / 4, 256, 0, stream>>>(hs1, offsets, csr, dinv, b1, h2);
    // layer 2
    k_gemm_mfma<unsigned short><<<(NN + 63) / 64, 256, 0, stream>>>(h2, Wt2, dinv, hs1);
    k_agg<<<(NN + 3) / 4, 256, 0, stream>>>(hs1, offsets, csr, dinv, b2, h3);
    // pool + FC
    k_pool<<<NG, 256, 0, stream>>>(h3, batch, pooled);
    k_fc<<<NG, 64, 0, stream>>>(pooled, Wfc, bfc, out);
}